// Round 12
// baseline (703.611 us; speedup 1.0000x reference)
//
#include <hip/hip_runtime.h>

#define HID 64
#define LL 16
#define NLAYERS 4
#define NN 50000
#define NE 200000
#define PRR 1600000
#define DDIM 100000        // PRR / LL
#define MGRPS 3125         // NN / 16
#define GE_BASE 800000     // ge rows appended to g after NN*16 rows
#define GROWS 800064
#define N2P_CNT PRR
#define E2P_CNT (PRR / 2)
#define POOL_CNT DDIM
#define TOTENT (N2P_CNT + E2P_CNT + POOL_CNT)   // 2.5M
#define NBINS (DDIM + NN)                        // 150000
#define QCAP 64
#define PCAP 16
#define GEMM_BLOCKS 196    // ceil(3125/16)
#define GATE_BLOCKS 782    // ceil(3125/4)

typedef __attribute__((ext_vector_type(8))) short bf16x8;
typedef __attribute__((ext_vector_type(4))) float f32x4;

__device__ __forceinline__ unsigned short f2bf(float x) {
    unsigned u = __float_as_uint(x);
    unsigned r = (u + 0x7fffu + ((u >> 16) & 1u)) >> 16;
    return (unsigned short)r;
}
__device__ __forceinline__ float bf2f(unsigned short v) {
    return __uint_as_float((unsigned)v << 16);
}

// ======================= CSR build (once per call) ==========================
__global__ void k_zero_i(int* __restrict__ b, int n) {
    int t = blockIdx.x * blockDim.x + threadIdx.x;
    if (t < n) b[t] = 0;
}

// single-pass padded fill: slot = atomicAdd(cnt[bin]); write into bin*CAP+slot
__global__ void k_fill_padded(
        const int* __restrict__ n2p_rows, const int* __restrict__ n2p_cols,
        const float* __restrict__ n2p_vals,
        const int* __restrict__ e2p_rows, const int* __restrict__ e2p_cols,
        const float* __restrict__ e2p_vals,
        const int* __restrict__ pool_rows, const int* __restrict__ pool_cols,
        const float* __restrict__ pool_vals,
        const int* __restrict__ edge_feat,
        int* __restrict__ cnt, uint2* __restrict__ entq, uint2* __restrict__ entp) {
    int k = blockIdx.x * blockDim.x + threadIdx.x;
    if (k >= TOTENT) return;
    if (k < N2P_CNT) {
        int r = n2p_rows[k];
        int bin = r >> 4;
        unsigned pay = (unsigned)n2p_cols[k] * 16u + (unsigned)(r & 15);
        int slot = atomicAdd(&cnt[bin], 1);
        slot = min(slot, QCAP - 1);
        entq[(size_t)bin * QCAP + slot] = make_uint2(pay, __float_as_uint(n2p_vals[k]));
    } else if (k < N2P_CNT + E2P_CNT) {
        int kk = k - N2P_CNT;
        int r = e2p_rows[kk];
        int bin = r >> 4;
        unsigned pay = (unsigned)GE_BASE + (unsigned)edge_feat[e2p_cols[kk]] * 16u
                     + (unsigned)(r & 15);
        int slot = atomicAdd(&cnt[bin], 1);
        slot = min(slot, QCAP - 1);
        entq[(size_t)bin * QCAP + slot] = make_uint2(pay, __float_as_uint(e2p_vals[kk]));
    } else {
        int kk = k - N2P_CNT - E2P_CNT;
        int bin = pool_rows[kk];
        int slot = atomicAdd(&cnt[DDIM + bin], 1);
        slot = min(slot, PCAP - 1);
        entp[(size_t)bin * PCAP + slot] =
            make_uint2((unsigned)pool_cols[kk], __float_as_uint(pool_vals[kk]));
    }
}

// ===================== upfront prep + h init (merged) =======================
#define WTB_SZ (LL * HID * HID)     // 65536
#define D1W_SZ (128 * HID)          // 8192
#define GE_SZ (4 * LL * HID)        // 4096
#define PER_LAYER (WTB_SZ + D1W_SZ + GE_SZ)   // 77824
#define PREP_BLOCKS ((NLAYERS * PER_LAYER + 255) / 256)   // 1216

__global__ void k_prep_init(const float* __restrict__ weights,
                            const float* __restrict__ bond_emb,
                            const float* __restrict__ deg1_w,
                            const int* __restrict__ node_feat,
                            const float* __restrict__ atom_emb,
                            unsigned short* __restrict__ wtB_all,
                            unsigned short* __restrict__ d1wB_all,
                            float* __restrict__ ge_all,
                            unsigned short* __restrict__ h16,
                            float* __restrict__ hf) {
    int bid = blockIdx.x;
    if (bid < PREP_BLOCKS) {
        int t = bid * 256 + threadIdx.x;
        if (t >= NLAYERS * PER_LAYER) return;
        int i = t / PER_LAYER;
        int u = t % PER_LAYER;
        const float* w_i = weights + (size_t)i * WTB_SZ;
        if (u < WTB_SZ) {
            int b = u & 63, N = u >> 6;
            int a = N >> 6, c = N & 63;
            wtB_all[(size_t)i * WTB_SZ + u] = f2bf(w_i[(b * HID + c) * LL + a]);
        } else if (u < WTB_SZ + D1W_SZ) {
            int v = u - WTB_SZ;
            d1wB_all[i * D1W_SZ + v] = f2bf(deg1_w[(size_t)i * D1W_SZ + v]);
        } else {
            int v = u - WTB_SZ - D1W_SZ;
            int c = v & 63, a = (v >> 6) & 15, ty = v >> 10;
            float s = 0.f;
            for (int b = 0; b < HID; ++b)
                s += bond_emb[i * 4 * HID + ty * HID + b] * w_i[(b * HID + c) * LL + a];
            ge_all[i * GE_SZ + v] = s;
        }
    } else {
        int t = (bid - PREP_BLOCKS) * 256 + threadIdx.x;
        if (t >= NN * HID) return;
        int n = t >> 6, c = t & 63;
        float v = atom_emb[node_feat[n] * HID + c];
        h16[t] = f2bf(v);
        hf[t] = v;
    }
}

// ======== merged per-layer matrix work: gemm | ge-copy | gate (by block) ====
__global__ void __launch_bounds__(256) k_gemm_gate(
        const unsigned short* __restrict__ h,
        const unsigned short* __restrict__ wtB,
        const float* __restrict__ ge_i,
        unsigned short* __restrict__ g,
        const float* __restrict__ degs,
        const float* __restrict__ d0w, const float* __restrict__ d0b,
        const unsigned short* __restrict__ d1wB, const float* __restrict__ d1b,
        float* __restrict__ gate) {
    int bid = blockIdx.x;
    int wave = threadIdx.x >> 6;
    int lane = threadIdx.x & 63;
    int mrow = lane & 15;
    int kgrp = lane >> 4;

    if (bid < GEMM_BLOCKS) {
        int mg4 = bid * 4 + wave;
        if (mg4 * 4 >= MGRPS) return;
        bf16x8 A0[4], A1[4];
        bool valid[4];
        #pragma unroll
        for (int i = 0; i < 4; ++i) {
            int mgrp = mg4 * 4 + i;
            valid[i] = (mgrp < MGRPS);
            if (valid[i]) {
                const unsigned short* hrow = h + ((size_t)mgrp * 16 + mrow) * HID;
                A0[i] = *(const bf16x8*)(hrow + kgrp * 8);
                A1[i] = *(const bf16x8*)(hrow + 32 + kgrp * 8);
            } else {
                bf16x8 z;
                #pragma unroll
                for (int tt = 0; tt < 8; ++tt) z[tt] = 0;
                A0[i] = z; A1[i] = z;
            }
        }
        const unsigned short* bp = wtB + (size_t)mrow * HID + kgrp * 8;
        unsigned short* gp[4];
        #pragma unroll
        for (int i = 0; i < 4; ++i)
            gp[i] = g + (size_t)((mg4 * 4 + i) * 16 + kgrp * 4) * 1024 + mrow;
        for (int ntile = 0; ntile < 64; ++ntile) {
            bf16x8 b0 = *(const bf16x8*)(bp);
            bf16x8 b1 = *(const bf16x8*)(bp + 32);
            #pragma unroll
            for (int i = 0; i < 4; ++i) {
                if (!valid[i]) continue;
                f32x4 acc = {0.f, 0.f, 0.f, 0.f};
                acc = __builtin_amdgcn_mfma_f32_16x16x32_bf16(A0[i], b0, acc, 0, 0, 0);
                acc = __builtin_amdgcn_mfma_f32_16x16x32_bf16(A1[i], b1, acc, 0, 0, 0);
                #pragma unroll
                for (int r = 0; r < 4; ++r)
                    gp[i][(size_t)r * 1024 + ntile * 16] = f2bf(acc[r]);
            }
            bp += 16 * HID;
        }
    } else if (bid == GEMM_BLOCKS) {
        for (int t = threadIdx.x; t < GE_SZ; t += 256)
            g[(size_t)(GE_BASE + (t >> 6)) * HID + (t & 63)] = f2bf(ge_i[t]);
    } else {
        int mgrp = (bid - GEMM_BLOCKS - 1) * 4 + wave;
        if (mgrp >= MGRPS) return;
        float deg = degs[mgrp * 16 + mrow];
        f32x4 acc[4];
        #pragma unroll
        for (int t = 0; t < 4; ++t) acc[t] = (f32x4){0.f, 0.f, 0.f, 0.f};
        #pragma unroll
        for (int s = 0; s < 4; ++s) {
            bf16x8 A;
            #pragma unroll
            for (int jj = 0; jj < 8; ++jj) {
                int k = s * 32 + kgrp * 8 + jj;
                A[jj] = (short)f2bf(fmaxf(deg * d0w[k] + d0b[k], 0.f));
            }
            #pragma unroll
            for (int t = 0; t < 4; ++t) {
                bf16x8 B = *(const bf16x8*)(d1wB + (t * 16 + mrow) * 128 + s * 32 + kgrp * 8);
                acc[t] = __builtin_amdgcn_mfma_f32_16x16x32_bf16(A, B, acc[t], 0, 0, 0);
            }
        }
        #pragma unroll
        for (int t = 0; t < 4; ++t) {
            float bb = d1b[t * 16 + mrow];
            #pragma unroll
            for (int r = 0; r < 4; ++r)
                gate[(size_t)(mgrp * 16 + kgrp * 4 + r) * HID + t * 16 + mrow] = acc[t][r] + bb;
        }
    }
}

// ===== gather q: wave per d; bin loaded ONCE coalesced (lane l = slot l);
// WAVE-UNIFORM loop bound (len uniform per wave) -> shfl always all-lanes-
// active; only the g-load is guarded by slot<len =============================
__global__ void __launch_bounds__(256) k_gather_q(
        const int* __restrict__ cnt, const uint2* __restrict__ entq,
        const unsigned short* __restrict__ g,
        const float* __restrict__ bias_i, float* __restrict__ qrelu) {
    int wid = (blockIdx.x * 256 + threadIdx.x) >> 6;
    if (wid >= DDIM) return;
    int lane = threadIdx.x & 63;
    int lp = lane & 15, grp = lane >> 4;
    int len = min(cnt[wid], QCAP);           // uniform across wave
    uint2 myent = entq[(size_t)wid * QCAP + lane];   // coalesced, 512B/wave
    float ac[4][4];
    #pragma unroll
    for (int t = 0; t < 4; ++t)
        #pragma unroll
        for (int q = 0; q < 4; ++q) ac[t][q] = 0.f;
    for (int base = 0; base < len; base += 16) {     // uniform condition
        #pragma unroll
        for (int t = 0; t < 4; ++t) {
            int slot = base + 4 * t + grp;
            int src = slot & 63;
            unsigned pay = (unsigned)__shfl((int)myent.x, src, 64);
            float v = __uint_as_float(__shfl((int)myent.y, src, 64));
            if (slot < len) {
                uint2 gv = *(const uint2*)(g + (size_t)pay * HID + 4 * lp);
                ac[t][0] += v * bf2f((unsigned short)(gv.x & 0xffffu));
                ac[t][1] += v * bf2f((unsigned short)(gv.x >> 16));
                ac[t][2] += v * bf2f((unsigned short)(gv.y & 0xffffu));
                ac[t][3] += v * bf2f((unsigned short)(gv.y >> 16));
            }
        }
    }
    float s0 = (ac[0][0] + ac[1][0]) + (ac[2][0] + ac[3][0]);
    float s1 = (ac[0][1] + ac[1][1]) + (ac[2][1] + ac[3][1]);
    float s2 = (ac[0][2] + ac[1][2]) + (ac[2][2] + ac[3][2]);
    float s3 = (ac[0][3] + ac[1][3]) + (ac[2][3] + ac[3][3]);
    s0 += __shfl_xor(s0, 16, 64); s0 += __shfl_xor(s0, 32, 64);
    s1 += __shfl_xor(s1, 16, 64); s1 += __shfl_xor(s1, 32, 64);
    s2 += __shfl_xor(s2, 16, 64); s2 += __shfl_xor(s2, 32, 64);
    s3 += __shfl_xor(s3, 16, 64); s3 += __shfl_xor(s3, 32, 64);
    if (grp == 0) {
        float4 b4 = *(const float4*)(bias_i + 4 * lp);
        float4 o = { fmaxf(s0 + b4.x, 0.f), fmaxf(s1 + b4.y, 0.f),
                     fmaxf(s2 + b4.z, 0.f), fmaxf(s3 + b4.w, 0.f) };
        *(float4*)(qrelu + (size_t)wid * HID + 4 * lp) = o;
    }
}

// ===== pool-gather x gate: shfls hoisted before the guard (all lanes active);
// writes h16 (bf16, gemm input) + hf (f32, reduce input) =====================
__global__ void __launch_bounds__(256) k_pool_gate(
        const int* __restrict__ cnt, const uint2* __restrict__ entp,
        const float* __restrict__ qrelu, const float* __restrict__ gate,
        unsigned short* __restrict__ h16, float* __restrict__ hf) {
    int wid = (blockIdx.x * 256 + threadIdx.x) >> 6;
    if (wid >= NN) return;
    int lane = threadIdx.x & 63;
    int lp = lane & 15, grp = lane >> 4;
    int len = min(cnt[DDIM + wid], PCAP);    // uniform across wave
    uint2 myent = entp[(size_t)wid * PCAP + lp];
    float s0 = 0.f, s1 = 0.f, s2 = 0.f, s3 = 0.f;
    #pragma unroll
    for (int t = 0; t < 4; ++t) {
        int slot = 4 * t + grp;              // 0..15
        unsigned pay = (unsigned)__shfl((int)myent.x, slot, 64);
        float v = __uint_as_float(__shfl((int)myent.y, slot, 64));
        if (slot < len) {
            float4 qv = *(const float4*)(qrelu + (size_t)pay * HID + 4 * lp);
            s0 += v * qv.x; s1 += v * qv.y; s2 += v * qv.z; s3 += v * qv.w;
        }
    }
    s0 += __shfl_xor(s0, 16, 64); s0 += __shfl_xor(s0, 32, 64);
    s1 += __shfl_xor(s1, 16, 64); s1 += __shfl_xor(s1, 32, 64);
    s2 += __shfl_xor(s2, 16, 64); s2 += __shfl_xor(s2, 32, 64);
    s3 += __shfl_xor(s3, 16, 64); s3 += __shfl_xor(s3, 32, 64);
    if (grp == 0) {
        float4 gt = *(const float4*)(gate + (size_t)wid * HID + 4 * lp);
        float4 of = { s0 * gt.x, s1 * gt.y, s2 * gt.z, s3 * gt.w };
        ushort4 o16 = { f2bf(of.x), f2bf(of.y), f2bf(of.z), f2bf(of.w) };
        *(float4*)(hf + (size_t)wid * HID + 4 * lp) = of;
        *(ushort4*)(h16 + (size_t)wid * HID + 4 * lp) = o16;
    }
}

// ============================== epilogue ====================================
__global__ void k_reduce(const float* __restrict__ hf,
                         float* __restrict__ partial_red) {
    __shared__ float lds[256];
    int tid = threadIdx.x;
    float s = 0.f;
    for (int idx = blockIdx.x * 256 + tid; idx < NN * HID; idx += gridDim.x * 256)
        s += hf[idx];
    lds[tid] = s;
    __syncthreads();
    if (tid < 64)
        partial_red[blockIdx.x * 64 + tid] = lds[tid] + lds[tid + 64] + lds[tid + 128] + lds[tid + 192];
}

__global__ void k_final(const float* __restrict__ partial_red,
                        const float* __restrict__ fw,
                        const float* __restrict__ fb, float* __restrict__ out) {
    int lane = threadIdx.x;
    float s = 0.f;
    for (int b = 0; b < 256; ++b) s += partial_red[b * 64 + lane];
    float v = s * (1.0f / NN) * fw[lane];
    for (int off = 32; off; off >>= 1) v += __shfl_down(v, off, 64);
    if (lane == 0) out[0] = v + fb[0];
}

// ============================================================================
extern "C" void kernel_launch(void* const* d_in, const int* in_sizes, int n_in,
                              void* d_out, int out_size, void* d_ws, size_t ws_size,
                              hipStream_t stream) {
    const int*   node_feat = (const int*)d_in[0];
    const int*   edge_feat = (const int*)d_in[1];
    const float* degs      = (const float*)d_in[2];
    const int*   n2p_rows  = (const int*)d_in[3];
    const int*   n2p_cols  = (const int*)d_in[4];
    const float* n2p_vals  = (const float*)d_in[5];
    const int*   e2p_rows  = (const int*)d_in[6];
    const int*   e2p_cols  = (const int*)d_in[7];
    const float* e2p_vals  = (const float*)d_in[8];
    const int*   pool_rows = (const int*)d_in[9];
    const int*   pool_cols = (const int*)d_in[10];
    const float* pool_vals = (const float*)d_in[11];
    const float* atom_emb  = (const float*)d_in[13];
    const float* bond_emb  = (const float*)d_in[14];
    const float* weights   = (const float*)d_in[15];
    const float* bias      = (const float*)d_in[16];
    const float* deg0_w    = (const float*)d_in[17];
    const float* deg0_b    = (const float*)d_in[18];
    const float* deg1_w    = (const float*)d_in[19];
    const float* deg1_b    = (const float*)d_in[20];
    const float* final_w   = (const float*)d_in[21];
    const float* final_b   = (const float*)d_in[22];
    float* out = (float*)d_out;

    char* wsb = (char*)d_ws;
    size_t off = 0;
    auto alloc = [&](size_t bytes) -> void* {
        void* ptr = wsb + off;
        off += (bytes + 255) & ~(size_t)255;
        return ptr;
    };
    unsigned short* h16      = (unsigned short*)alloc((size_t)NN * HID * 2);      // 6.4 MB
    float*          hf       = (float*)alloc((size_t)NN * HID * 4);               // 12.8 MB
    unsigned short* g        = (unsigned short*)alloc((size_t)GROWS * HID * 2);   // 102.4 MB
    float*          qrelu    = (float*)alloc((size_t)DDIM * HID * 4);             // 25.6 MB
    float*          gate     = (float*)alloc((size_t)NN * HID * 4);               // 12.8 MB
    unsigned short* wtB_all  = (unsigned short*)alloc((size_t)NLAYERS * WTB_SZ * 2);
    unsigned short* d1wB_all = (unsigned short*)alloc((size_t)NLAYERS * D1W_SZ * 2);
    float*          ge_all   = (float*)alloc((size_t)NLAYERS * GE_SZ * 4);
    float*          partial_red = (float*)alloc(256 * 64 * 4);
    int*            cnt      = (int*)alloc((size_t)NBINS * 4);                    // 0.6 MB
    uint2*          entq     = (uint2*)alloc((size_t)DDIM * QCAP * 8);            // 51.2 MB
    uint2*          entp     = (uint2*)alloc((size_t)NN * PCAP * 8);              // 6.4 MB

    // ---------------- CSR build: zero + single fused pass --------------------
    k_zero_i<<<(NBINS + 255) / 256, 256, 0, stream>>>(cnt, NBINS);
    k_fill_padded<<<(TOTENT + 255) / 256, 256, 0, stream>>>(
        n2p_rows, n2p_cols, n2p_vals, e2p_rows, e2p_cols, e2p_vals,
        pool_rows, pool_cols, pool_vals, edge_feat, cnt, entq, entp);

    // ---------------- prep + init (merged) -----------------------------------
    int init_blocks = (NN * HID + 255) / 256;
    k_prep_init<<<PREP_BLOCKS + init_blocks, 256, 0, stream>>>(
        weights, bond_emb, deg1_w, node_feat, atom_emb,
        wtB_all, d1wB_all, ge_all, h16, hf);

    // ---------------- layers -------------------------------------------------
    for (int i = 0; i < NLAYERS; ++i) {
        k_gemm_gate<<<GEMM_BLOCKS + 1 + GATE_BLOCKS, 256, 0, stream>>>(
            h16, wtB_all + (size_t)i * WTB_SZ, ge_all + (size_t)i * GE_SZ, g,
            degs, deg0_w + i * 2 * HID, deg0_b + i * 2 * HID,
            d1wB_all + (size_t)i * D1W_SZ, deg1_b + i * HID, gate);
        k_gather_q<<<(DDIM + 3) / 4, 256, 0, stream>>>(
            cnt, entq, g, bias + i * HID, qrelu);
        k_pool_gate<<<(NN + 3) / 4, 256, 0, stream>>>(
            cnt, entp, qrelu, gate, h16, hf);
    }

    k_reduce<<<256, 256, 0, stream>>>(hf, partial_red);
    k_final<<<1, 64, 0, stream>>>(partial_red, final_w, final_b, out);
}